// Round 16
// baseline (241.756 us; speedup 1.0000x reference)
//
#include <hip/hip_runtime.h>

#define HW (512 * 512)
#define QP 260   // pitch (floats): >=256, %4==0 (b128-clean), %32==4 staggers row banks
#define WN 12288 // 192*64

typedef __bf16 bf16;
typedef __attribute__((ext_vector_type(8))) __bf16 bf16x8;
typedef __attribute__((ext_vector_type(4))) float f32x4;

__device__ __forceinline__ void cvt_split(float f, bf16& h, bf16& l) {
    h = (bf16)f;
    l = (bf16)(f - (float)h);
}

// pack f32 -> u32 = (bf16 hi << 16) | bf16 lo (hi = truncated top-16, lo = RNE remainder)
__device__ __forceinline__ unsigned int pack_hl(float x) {
    const unsigned int hx = __float_as_uint(x) & 0xFFFF0000u;
    const float lof = x - __uint_as_float(hx);
    const bf16 lb = (bf16)lof;
    return hx | (unsigned int)__builtin_bit_cast(unsigned short, lb);
}

// unpack 8 packed u32 (px-consecutive) into hi-plane and lo-plane bf16x8 fragments.
__device__ __forceinline__ void unpack8(const uint4 a0, const uint4 a1,
                                        bf16x8& hv, bf16x8& lv) {
    union { unsigned int u[4]; bf16x8 v; } H, L;
    H.u[0] = __builtin_amdgcn_perm(a0.y, a0.x, 0x07060302u);
    L.u[0] = __builtin_amdgcn_perm(a0.y, a0.x, 0x05040100u);
    H.u[1] = __builtin_amdgcn_perm(a0.w, a0.z, 0x07060302u);
    L.u[1] = __builtin_amdgcn_perm(a0.w, a0.z, 0x05040100u);
    H.u[2] = __builtin_amdgcn_perm(a1.y, a1.x, 0x07060302u);
    L.u[2] = __builtin_amdgcn_perm(a1.y, a1.x, 0x05040100u);
    H.u[3] = __builtin_amdgcn_perm(a1.w, a1.z, 0x07060302u);
    L.u[3] = __builtin_amdgcn_perm(a1.w, a1.z, 0x05040100u);
    hv = H.v; lv = L.v;
}

// wave-uniform broadcast of lane `l` (compile-time const) of v — v_readlane -> SGPR
__device__ __forceinline__ float rdl(float v, int l) {
    return __uint_as_float(__builtin_amdgcn_readlane(__float_as_uint(v), l));
}

// Precompute: W -> bf16 hi/lo planes in d_ws (48 KB, L2-resident). (verified R8+)
__global__ __launch_bounds__(256) void wcvt_kernel(
    const float* __restrict__ w, bf16* __restrict__ wh, bf16* __restrict__ wl)
{
    const int i = blockIdx.x * 256 + threadIdx.x;
    if (i < WN) {
        bf16 h, l;
        cvt_split(w[i], h, l);
        wh[i] = h;
        wl[i] = l;
    }
}

// R16 = R15 (2 win/block, MFMA kv, best @236us) with the kv_s LDS round-trip removed:
// after S3 every wave folds kvp into ONE register per window (lane l = kv[l], 8 b32),
// and phase D broadcasts via compile-time v_readlane (SGPR) instead of 32 b128 LDS
// broadcast reads. Cuts ~430 LDS cyc/wave-head and shortens the S3->S4->D chain.
// Race audit: kvsum reads pre-S4; kvp next written post-S4 (B(h+1)); tp parity ok.
// No forced reg cap (R4/R5/R9: cap below natural demand => spill traffic).
__global__ __launch_bounds__(256, 2) void lwmsa_kernel(
    const float* __restrict__ x,
    const bf16* __restrict__ wh,
    const bf16* __restrict__ wl,
    float* __restrict__ out)
{
    const int blk  = blockIdx.x;       // 0..2047
    const int b    = blk >> 9;
    const int wrow = (blk >> 4) & 31;
    const int wp   = blk & 15;         // col pair: wcol = 2*wp + w
    const int n    = threadIdx.x;      // 0..255 = pixel in window
    const int lane = n & 63;
    const int wvid = n >> 6;           // wave 0..3
    const int c16  = lane & 15;
    const int q4   = lane >> 4;

    __shared__ float qk[2][24 * QP];   // per window: q rows 0-7, k 8-15, v 16-23
    __shared__ float kvp[2][256];      // per window: per-wave kv partials [wave][d*8+c]
    __shared__ float tp[2][2][4];      // [win][parity][wave]

    int base[2], xwin[2];
    #pragma unroll
    for (int w = 0; w < 2; ++w) {
        const int wcol = wp * 2 + w;
        base[w] = b * (64 * HW) + (wrow * 16 + (n >> 4)) * 512 + wcol * 16 + (n & 15);
        xwin[w] = b * (64 * HW) + (wrow * 16) * 512 + wcol * 16;
    }

    // ---- A-fragments (X) for both windows, hi/lo, global -> registers ----
    bf16x8 ah[2][2][4], al[2][2][4];   // [win][ks][mt]
    #pragma unroll
    for (int w = 0; w < 2; ++w)
        #pragma unroll
        for (int ks = 0; ks < 2; ++ks)
            #pragma unroll
            for (int mt = 0; mt < 4; ++mt) {
                const int row = wvid * 4 + mt;
                const float* xp = x + xwin[w] + row * 512 + c16 + (ks * 32 + q4 * 8) * HW;
                #pragma unroll
                for (int j = 0; j < 8; ++j) {
                    bf16 h, l;
                    cvt_split(xp[j * HW], h, l);
                    ah[w][ks][mt][j] = h;
                    al[w][ks][mt][j] = l;
                }
            }

    // ---- per-head MFMA + stage into qk[w]: 24 rows (q0-7,k8-15,v16-23) ----
    auto mfma_stage = [&](int w, int hh) {
        f32x4 acc[4][2];
        #pragma unroll
        for (int mt = 0; mt < 4; ++mt)
            #pragma unroll
            for (int nt = 0; nt < 2; ++nt)
                acc[mt][nt] = (f32x4){0.f, 0.f, 0.f, 0.f};

        #pragma unroll
        for (int ks = 0; ks < 2; ++ks) {
            #pragma unroll
            for (int nt = 0; nt < 2; ++nt) {
                const int ml   = nt * 16 + c16;                 // 0..31; valid < 24
                const int grow = (ml < 24) ? ((ml >> 3) * 64 + hh * 8 + (ml & 7))
                                           : (hh * 8);          // in-bounds dummy
                const int off  = grow * 64 + ks * 32 + q4 * 8;
                const bf16x8 bh = *(const bf16x8*)&wh[off];
                const bf16x8 bl = *(const bf16x8*)&wl[off];
                #pragma unroll
                for (int mt = 0; mt < 4; ++mt) {
                    acc[mt][nt] = __builtin_amdgcn_mfma_f32_16x16x32_bf16(ah[w][ks][mt], bh, acc[mt][nt], 0, 0, 0);
                    acc[mt][nt] = __builtin_amdgcn_mfma_f32_16x16x32_bf16(al[w][ks][mt], bh, acc[mt][nt], 0, 0, 0);
                    acc[mt][nt] = __builtin_amdgcn_mfma_f32_16x16x32_bf16(ah[w][ks][mt], bl, acc[mt][nt], 0, 0, 0);
                }
            }
        }

        #pragma unroll
        for (int nt = 0; nt < 2; ++nt) {
            const int ml = nt * 16 + c16;
            if (ml < 24) {
                #pragma unroll
                for (int mt = 0; mt < 4; ++mt) {
                    const int px = (wvid * 4 + mt) * 16 + q4 * 4;
                    *(float4*)&qk[w][ml * QP + px] = *(float4*)&acc[mt][nt];
                }
            }
        }
    };

    float feat[2][8];
    #pragma unroll
    for (int w = 0; w < 2; ++w)
        #pragma unroll
        for (int d = 0; d < 8; ++d) feat[w][d] = 0.f;

    mfma_stage(0, 0);
    mfma_stage(1, 0);
    __syncthreads();  // S_init: head-0 projections of both windows visible

    for (int h = 0; h < 8; ++h) {
        // ---- phase A (x2): proj+feat, elu1, sums; write PACKED kf/av (own column) ----
        float qf[2][8], Sq[2], tpart[2];
        #pragma unroll
        for (int w = 0; w < 2; ++w) {
            Sq[w] = 0.f; tpart[w] = 0.f;
            unsigned int* qku = (unsigned int*)qk[w];
            #pragma unroll
            for (int d = 0; d < 8; ++d) {
                const float aq = qk[w][d * QP + n]        + feat[w][d];
                const float ak = qk[w][(8 + d) * QP + n]  + feat[w][d];
                const float av = qk[w][(16 + d) * QP + n] + feat[w][d];
                qf[w][d] = aq > 0.f ? aq + 1.f : __expf(aq);
                const float kf = ak > 0.f ? ak + 1.f : __expf(ak);
                Sq[w]    += qf[w][d];
                tpart[w] += kf;
                qku[(8 + d) * QP + n]  = pack_hl(kf);   // own column: no hazard
                qku[(16 + d) * QP + n] = pack_hl(av);
            }
        }

        #pragma unroll
        for (int off = 1; off < 64; off <<= 1) {
            tpart[0] += __shfl_xor(tpart[0], off, 64);
            tpart[1] += __shfl_xor(tpart[1], off, 64);
        }
        if (lane == 0) {
            tp[0][h & 1][wvid] = tpart[0];
            tp[1][h & 1][wvid] = tpart[1];
        }

        // wave-internal handoff: phase B reads only this wave's 64 columns (R8-verified)
        asm volatile("s_waitcnt lgkmcnt(0)" ::: "memory");

        // ---- phase B (x2): kv via MFMA over this wave's 64 px ----
        #pragma unroll
        for (int w = 0; w < 2; ++w) {
            const unsigned int* qku = (const unsigned int*)qk[w];
            f32x4 kvacc = (f32x4){0.f, 0.f, 0.f, 0.f};
            const int arow = 8  + (c16 & 7);    // kf row d (rows 8-15 duplicate 0-7)
            const int brow = 16 + (c16 & 7);    // av row c
            #pragma unroll
            for (int s = 0; s < 2; ++s) {
                const int off = wvid * 64 + s * 32 + q4 * 8;
                const uint4 pa0 = *(const uint4*)(qku + arow * QP + off);
                const uint4 pa1 = *(const uint4*)(qku + arow * QP + off + 4);
                const uint4 pb0 = *(const uint4*)(qku + brow * QP + off);
                const uint4 pb1 = *(const uint4*)(qku + brow * QP + off + 4);
                bf16x8 kah, kal, bvh, bvl;
                unpack8(pa0, pa1, kah, kal);
                unpack8(pb0, pb1, bvh, bvl);
                kvacc = __builtin_amdgcn_mfma_f32_16x16x32_bf16(kah, bvh, kvacc, 0, 0, 0);
                kvacc = __builtin_amdgcn_mfma_f32_16x16x32_bf16(kah, bvl, kvacc, 0, 0, 0);
                kvacc = __builtin_amdgcn_mfma_f32_16x16x32_bf16(kal, bvh, kvacc, 0, 0, 0);
            }
            // D: col=c16=c, row=q4*4+reg=d; valid 8x8 -> kvp[wave][d*8+c]
            if (c16 < 8 && q4 < 2) {
                #pragma unroll
                for (int r = 0; r < 4; ++r)
                    kvp[w][wvid * 64 + (q4 * 4 + r) * 8 + c16] = kvacc[r];
            }
        }

        __syncthreads();  // S3: kvp + tp visible; qk buffers dead -> restage allowed

        // ---- kv fold (pre-S4, every wave): lane l holds kv[l] per window ----
        const float kvr0 = (kvp[0][lane] + kvp[0][64 + lane]) +
                           (kvp[0][128 + lane] + kvp[0][192 + lane]);
        const float kvr1 = (kvp[1][lane] + kvp[1][64 + lane]) +
                           (kvp[1][128 + lane] + kvp[1][192 + lane]);

        if (h < 7) {
            mfma_stage(0, h + 1);
            mfma_stage(1, h + 1);
        }

        __syncthreads();  // S4: next head's projections visible

        // ---- phase D (x2): register-only — readlane kv broadcast, z, feat, out ----
        #pragma unroll
        for (int w = 0; w < 2; ++w) {
            const float kvr = w ? kvr1 : kvr0;
            const float T  = ((tp[w][h & 1][0] + tp[w][h & 1][1]) +
                              (tp[w][h & 1][2] + tp[w][h & 1][3])) + 8.0f * 1e-6f;
            const float zi = 1.0f / (Sq[w] * T);

            float ft[8];
            #pragma unroll
            for (int c = 0; c < 8; ++c) ft[c] = 0.f;
            #pragma unroll
            for (int d = 0; d < 8; ++d) {
                const float qd = qf[w][d];
                #pragma unroll
                for (int c = 0; c < 8; ++c)
                    ft[c] = fmaf(qd, rdl(kvr, d * 8 + c), ft[c]);
            }
            #pragma unroll
            for (int d = 0; d < 8; ++d) {
                feat[w][d] = ft[d] * zi;
                out[base[w] + (h * 8 + d) * HW] = feat[w][d];
            }
        }
    }
}

extern "C" void kernel_launch(void* const* d_in, const int* in_sizes, int n_in,
                              void* d_out, int out_size, void* d_ws, size_t ws_size,
                              hipStream_t stream) {
    const float* x  = (const float*)d_in[0];
    const float* w  = (const float*)d_in[1];
    float* out      = (float*)d_out;
    bf16* wh = (bf16*)d_ws;
    bf16* wl = wh + WN;
    wcvt_kernel<<<dim3((WN + 255) / 256), dim3(256), 0, stream>>>(w, wh, wl);
    lwmsa_kernel<<<dim3(2048), dim3(256), 0, stream>>>(x, wh, wl, out);
}